// Round 11
// baseline (123.564 us; speedup 1.0000x reference)
//
#include <hip/hip_runtime.h>
#include <hip/hip_bf16.h>
#include <math.h>

typedef __bf16 bf16x8 __attribute__((ext_vector_type(8)));
typedef float f32x4 __attribute__((ext_vector_type(4)));
typedef float f32x16 __attribute__((ext_vector_type(16)));
typedef unsigned short u16x8 __attribute__((ext_vector_type(8)));
typedef unsigned int u32x4 __attribute__((ext_vector_type(4)));
typedef _Float16 h16x4 __attribute__((ext_vector_type(4)));
typedef unsigned short u16;

#define S_LEN 2048
#define DMODEL 1024
#define NH 16
#define NROWS 65536   // 2*16*2048 (b,h,s) rows

__device__ __forceinline__ u16 f2bf(float f) {
    __bf16 b = (__bf16)f;
    return __builtin_bit_cast(u16, b);
}
__device__ __forceinline__ float bf2f(u16 u) {
    union { unsigned int i; float f; } v; v.i = ((unsigned int)u) << 16; return v.f;
}
__device__ __forceinline__ unsigned int pk2(float a, float b) {
    return (unsigned int)f2bf(a) | ((unsigned int)f2bf(b) << 16);
}

// global -> LDS direct copy, 16B per lane (wave-uniform LDS base + lane*16).
__device__ __forceinline__ void gload16(const u16* g, u16* lds_base) {
    __builtin_amdgcn_global_load_lds(
        (const __attribute__((address_space(1))) unsigned int*)g,
        (__attribute__((address_space(3))) unsigned int*)lds_base,
        16, 0, 0);
}

// ---------- X f32 -> bf16 ----------
__global__ __launch_bounds__(256) void cvt_x(const float* __restrict__ in, u16* __restrict__ outp) {
    int i = (blockIdx.x * 256 + threadIdx.x) * 4;
    float4 v = *(const float4*)(in + i);
    outp[i + 0] = f2bf(v.x); outp[i + 1] = f2bf(v.y);
    outp[i + 2] = f2bf(v.z); outp[i + 3] = f2bf(v.w);
}

// ---------- W [1024][3072] f32 -> Wt [3072][1024] bf16 ----------
__global__ __launch_bounds__(256) void transpose_w(const float* __restrict__ W, u16* __restrict__ Wt) {
    __shared__ u16 tile[32][33];
    int n0 = blockIdx.x * 32, k0 = blockIdx.y * 32;
    int tx = threadIdx.x & 31, ty = threadIdx.x >> 5;
#pragma unroll
    for (int i = 0; i < 4; i++) {
        int k = ty + i * 8;
        tile[k][tx] = f2bf(W[(size_t)(k0 + k) * 3072 + n0 + tx]);
    }
    __syncthreads();
#pragma unroll
    for (int i = 0; i < 4; i++) {
        int n = ty + i * 8;
        Wt[(size_t)(n0 + n) * 1024 + k0 + tx] = tile[tx][n];
    }
}

// ---------- QKV GEMM (unchanged) ----------
__global__ __launch_bounds__(256) void qkv_gemm(const u16* __restrict__ A, const u16* __restrict__ Bt,
                                                u16* __restrict__ C) {
    __shared__ alignas(16) u16 As[128 * 64];
    __shared__ alignas(16) u16 Bs[128 * 64];
    const int tid = threadIdx.x, l = tid & 63, w = tid >> 6;
    const int bm = blockIdx.y, bn = blockIdx.x;
    const int wm = w >> 1, wn = w & 1;
    const int c0 = l & 15, g = l >> 4;
    f32x4 acc[4][4] = {};
    for (int kt = 0; kt < 1024; kt += 64) {
        __syncthreads();
#pragma unroll
        for (int n = 0; n < 4; n++) {
            int i = tid + n * 256;
            int r = i >> 3, c = i & 7;
            int cs = c ^ (r & 7);
            u16* dstA = As + (size_t)(w * 64 + n * 256) * 8;
            u16* dstB = Bs + (size_t)(w * 64 + n * 256) * 8;
            gload16(A + (size_t)(bm * 128 + r) * 1024 + kt + cs * 8, dstA);
            gload16(Bt + (size_t)(bn * 128 + r) * 1024 + kt + cs * 8, dstB);
        }
        __syncthreads();
#pragma unroll
        for (int kk = 0; kk < 2; kk++) {
            bf16x8 af[4], bfr[4];
#pragma unroll
            for (int m = 0; m < 4; m++) {
                int row = wm * 64 + m * 16 + c0;
                af[m] = *(const bf16x8*)((const char*)As + row * 128 + (((g + kk * 4) ^ (row & 7)) << 4));
            }
#pragma unroll
            for (int n = 0; n < 4; n++) {
                int row = wn * 64 + n * 16 + c0;
                bfr[n] = *(const bf16x8*)((const char*)Bs + row * 128 + (((g + kk * 4) ^ (row & 7)) << 4));
            }
#pragma unroll
            for (int m = 0; m < 4; m++)
#pragma unroll
                for (int n = 0; n < 4; n++)
                    acc[m][n] = __builtin_amdgcn_mfma_f32_16x16x32_bf16(af[m], bfr[n], acc[m][n], 0, 0, 0);
        }
    }
#pragma unroll
    for (int m = 0; m < 4; m++)
#pragma unroll
        for (int n = 0; n < 4; n++)
#pragma unroll
            for (int j = 0; j < 4; j++) {
                int row = bm * 128 + wm * 64 + m * 16 + 4 * g + j;
                int col = bn * 128 + wn * 64 + n * 16 + c0;
                C[(size_t)row * 3072 + col] = f2bf(acc[m][n][j]);
            }
}

// ---------- V -> plain V^T: Vtp[bh][d][s] (32x32 B-frags are key-contiguous; R8-verified) ----------
__global__ __launch_bounds__(256) void transpose_v(const u16* __restrict__ QKV, u16* __restrict__ Vtp) {
    __shared__ u16 tile[64][72];
    const int bh = blockIdx.x >> 5, st = blockIdx.x & 31;
    const int b = bh >> 4, h = bh & 15;
    const u16* src = QKV + (size_t)b * S_LEN * 3072 + 2048 + h * 64;
    const int sl = threadIdx.x >> 2;
    const int cg = (threadIdx.x & 3) * 16;
#pragma unroll
    for (int ii = 0; ii < 2; ii++) {
        u16x8 v = *(const u16x8*)(src + (size_t)(st * 64 + sl) * 3072 + cg + ii * 8);
        *(u16x8*)&tile[sl][cg + ii * 8] = v;
    }
    __syncthreads();
    const int dl = threadIdx.x >> 2;
#pragma unroll
    for (int ii = 0; ii < 2; ii++) {
        u16x8 o;
#pragma unroll
        for (int q = 0; q < 8; q++) {
            int p = cg + ii * 8 + q;
            o[q] = tile[p][dl];
        }
        *(u16x8*)(Vtp + ((size_t)bh * 64 + dl) * S_LEN + st * 64 + cg + ii * 8) = o;
    }
}

// ---------- Flash attention v10b: 32x32x16 MFMA + KV-split x2 across blocks + baked -m_r
// + lane-local defer + ones-MFMA l + v_permlane32_swap_b32 half-exchange.
// FIX vs R10: swap operand order — vdst must be gA (y), vsrc gB (x):
//   v_permlane32_swap_b32 y, x   =>  y[32:63] <-> x[0:31]
//   y_new = [own gA | partner-lo gB] = pu[0];  x_new = [partner-hi gA | own gB] = pu[2].
__global__ __launch_bounds__(256, 2) void attn10(const u16* __restrict__ QKV, const u16* __restrict__ Vtp,
                                                 float* __restrict__ outp, _Float16* __restrict__ Op1,
                                                 float* __restrict__ Mp, float* __restrict__ Lp) {
    __shared__ alignas(16) u16 Ks[2][64 * 64];   // [key][d-chunk], chunk^=(key&7)
    __shared__ alignas(16) u16 Vs[2][64 * 64];   // [d][pos-chunk], chunk^=(d&7)
    const int bid = blockIdx.x;
    const int wg = ((bid & 7) << 7) | (bid >> 3);   // 1024 = 8*128, bijective XCD swizzle
    const int tid = threadIdx.x, l = tid & 63, w = tid >> 6;
    const int bh = wg >> 5, rest = wg & 31;
    const int qt = rest >> 1, hf = rest & 1;        // qt in [0,16): 128 q/block; hf = KV half
    const int b = bh >> 4, h = bh & 15;
    const int l5 = l & 31, hi = l >> 5;
    const u16* Qb = QKV + (size_t)b * S_LEN * 3072 + h * 64;
    const u16* Kb = Qb + 1024;
    const u16* Vb = Vtp + (size_t)bh * 64 * S_LEN;
    const int kv0 = hf * 1024;
    const int qbase = qt * 128 + w * 32;

    // staging: chunks {tid, tid+256} (rows 0-31 / 32-63), pre-swizzled source col
    const int r0 = tid >> 3, cs0 = (tid & 7) ^ (r0 & 7);
    const int i1 = tid + 256, r1 = i1 >> 3, cs1 = (i1 & 7) ^ (r1 & 7);
    const int dbA = (w * 64) * 8, dbB = (256 + w * 64) * 8;

    // LDS read byte-offsets: off[x][ks] serves K (x=kb) and V (x=d0-tile)
    int off[2][4];
#pragma unroll
    for (int x = 0; x < 2; x++)
#pragma unroll
        for (int ks = 0; ks < 4; ks++)
            off[x][ks] = (x * 32 + l5) * 128 + (((2 * ks + hi) ^ (l5 & 7)) << 4);

    // Q B-frags: qf[ks][j] = Q[qbase+l5][16ks + 8hi + j] * scale (fold (1/8)*log2e)
    bf16x8 qf[4];
    {
        const float qs = 0.125f * 1.44269504f;
#pragma unroll
        for (int ks = 0; ks < 4; ks++) {
            u16x8 v = *(const u16x8*)(Qb + (size_t)(qbase + l5) * 3072 + ks * 16 + hi * 8);
            bf16x8 q;
#pragma unroll
            for (int j = 0; j < 8; j++) q[j] = (__bf16)(bf2f(v[j]) * qs);
            qf[ks] = q;
        }
    }
    bf16x8 vone;
#pragma unroll
    for (int j = 0; j < 8; j++) vone[j] = (__bf16)1.0f;

    float m_r = 0.f;   // baked scheme: sck accumulates S - m_r (per-lane q = l5)
    f32x16 accO0 = {}, accO1 = {}, accL = {};

    // prologue: stage tile kv0 into buf 0
    gload16(Kb + (size_t)(kv0 + r0) * 3072 + cs0 * 8, Ks[0] + dbA);
    gload16(Kb + (size_t)(kv0 + r1) * 3072 + cs1 * 8, Ks[0] + dbB);
    gload16(Vb + (size_t)r0 * S_LEN + kv0 + cs0 * 8, Vs[0] + dbA);
    gload16(Vb + (size_t)r1 * S_LEN + kv0 + cs1 * 8, Vs[0] + dbB);

    for (int t = 0; t < 16; t++) {
        const int cur = t & 1;
        __syncthreads();
        if (t + 1 < 16) {
            const int kvn = kv0 + (t + 1) * 64;
            gload16(Kb + (size_t)(kvn + r0) * 3072 + cs0 * 8, Ks[cur ^ 1] + dbA);
            gload16(Kb + (size_t)(kvn + r1) * 3072 + cs1 * 8, Ks[cur ^ 1] + dbB);
            gload16(Vb + (size_t)r0 * S_LEN + kvn + cs0 * 8, Vs[cur ^ 1] + dbA);
            gload16(Vb + (size_t)r1 * S_LEN + kvn + cs1 * 8, Vs[cur ^ 1] + dbB);
        }
        const char* Kc = (const char*)Ks[cur];
        const char* Vc = (const char*)Vs[cur];
        // QK^T swapped, C-in = -m_r: sck = S - m_r directly. sck[kb]=C[key=32kb+crow][q=l5]
        f32x16 sck0, sck1;
        const float nm = -m_r;
#pragma unroll
        for (int r = 0; r < 16; r++) { sck0[r] = nm; sck1[r] = nm; }
        __builtin_amdgcn_s_setprio(1);
#pragma unroll
        for (int ks = 0; ks < 4; ks++) {
            bf16x8 kf0 = *(const bf16x8*)(Kc + off[0][ks]);
            bf16x8 kf1 = *(const bf16x8*)(Kc + off[1][ks]);
            sck0 = __builtin_amdgcn_mfma_f32_32x32x16_bf16(kf0, qf[ks], sck0, 0, 0, 0);
            sck1 = __builtin_amdgcn_mfma_f32_32x32x16_bf16(kf1, qf[ks], sck1, 0, 0, 0);
        }
        __builtin_amdgcn_s_setprio(0);
        // lane-local max of baked scores (no cross-lane in common path)
        float mx;
        {
            float a0 = fmaxf(fmaxf(sck0[0], sck0[1]), sck0[2]);
            float a1 = fmaxf(fmaxf(sck0[3], sck0[4]), sck0[5]);
            float a2 = fmaxf(fmaxf(sck0[6], sck0[7]), sck0[8]);
            float a3 = fmaxf(fmaxf(sck0[9], sck0[10]), sck0[11]);
            float a4 = fmaxf(fmaxf(sck0[12], sck0[13]), sck0[14]);
            float a5 = fmaxf(fmaxf(sck0[15], sck1[0]), sck1[1]);
            float a6 = fmaxf(fmaxf(sck1[2], sck1[3]), sck1[4]);
            float a7 = fmaxf(fmaxf(sck1[5], sck1[6]), sck1[7]);
            float a8 = fmaxf(fmaxf(sck1[8], sck1[9]), sck1[10]);
            float a9 = fmaxf(fmaxf(sck1[11], sck1[12]), sck1[13]);
            float aa = fmaxf(sck1[14], sck1[15]);
            mx = fmaxf(fmaxf(fmaxf(fmaxf(a0, a1), fmaxf(a2, a3)), fmaxf(fmaxf(a4, a5), fmaxf(a6, a7))),
                       fmaxf(fmaxf(a8, a9), aa));
        }
        // defer-max: rescale only when some lane's local growth exceeds 8 (log2 domain)
        if (!__all(mx <= 8.f)) {
            float mxr = fmaxf(mx, __shfl_xor(mx, 32));   // full row max for q=l5 (uniform across hi)
            float adj = fmaxf(mxr, 0.f);
            float alpha = __builtin_amdgcn_exp2f(-adj);
            m_r += adj;
#pragma unroll
            for (int r = 0; r < 16; r++) {
                int cr = (r & 3) + 8 * (r >> 2) + 4 * hi;    // q-row of acc reg r
                float ar = __shfl(alpha, cr);
                accL[r] *= ar; accO0[r] *= ar; accO1[r] *= ar;
            }
#pragma unroll
            for (int r = 0; r < 16; r++) { sck0[r] -= adj; sck1[r] -= adj; }
        }
        // P = exp2(baked scores)
#pragma unroll
        for (int r = 0; r < 16; r++) {
            sck0[r] = __builtin_amdgcn_exp2f(sck0[r]);
            sck1[r] = __builtin_amdgcn_exp2f(sck1[r]);
        }
        // PV + l: per ks, pack -> permlane32_swap (vdst=gA, vsrc=gB) -> A-frag
        __builtin_amdgcn_s_setprio(1);
#pragma unroll
        for (int ks = 0; ks < 4; ks++) {
            const int t2 = ks & 1;
            const f32x16& s = (ks & 2) ? sck1 : sck0;
            const int ue = 8 * t2, uo = ue + 4;
            unsigned int y0 = pk2(s[ue + 0], s[ue + 1]);   // gA word 0 (regs u=2t2)
            unsigned int y1 = pk2(s[ue + 2], s[ue + 3]);   // gA word 1
            unsigned int x0 = pk2(s[uo + 0], s[uo + 1]);   // gB word 0 (regs u=2t2+1)
            unsigned int x1 = pk2(s[uo + 2], s[uo + 3]);   // gB word 1
            // y[32:63] <-> x[0:31]:
            //   y_new = [own gA | partner-lo gB] -> pu[0];  x_new = [partner-hi gA | own gB] -> pu[2]
            asm("v_permlane32_swap_b32 %0, %1" : "+v"(y0), "+v"(x0));
            asm("v_permlane32_swap_b32 %0, %1" : "+v"(y1), "+v"(x1));
            u32x4 pu; pu[0] = y0; pu[1] = y1; pu[2] = x0; pu[3] = x1;
            bf16x8 pf = __builtin_bit_cast(bf16x8, pu);
            bf16x8 vf0 = *(const bf16x8*)(Vc + off[0][ks]);
            bf16x8 vf1 = *(const bf16x8*)(Vc + off[1][ks]);
            accL  = __builtin_amdgcn_mfma_f32_32x32x16_bf16(pf, vone, accL, 0, 0, 0);
            accO0 = __builtin_amdgcn_mfma_f32_32x32x16_bf16(pf, vf0, accO0, 0, 0, 0);
            accO1 = __builtin_amdgcn_mfma_f32_32x32x16_bf16(pf, vf1, accO1, 0, 0, 0);
        }
        __builtin_amdgcn_s_setprio(0);
    }
    // epilogue: acc reg r -> q = qbase + cr, cols d = {l5, 32+l5}; accL[r] = row-sum
    const int rowg0 = bh * 2048 + qbase;
    if (hf == 0) {
#pragma unroll
        for (int r = 0; r < 16; r++) {
            int cr = (r & 3) + 8 * (r >> 2) + 4 * hi;
            float inv = 1.0f / accL[r];
            float* op = outp + ((size_t)b * S_LEN + qbase + cr) * DMODEL + h * 64;
            op[l5] = accO0[r] * inv;
            op[32 + l5] = accO1[r] * inv;
        }
    } else {
#pragma unroll
        for (int r = 0; r < 16; r++) {
            int cr = (r & 3) + 8 * (r >> 2) + 4 * hi;
            float inv = 1.0f / accL[r];
            _Float16* op = Op1 + (size_t)(rowg0 + cr) * 64;
            op[l5] = (_Float16)(accO0[r] * inv);
            op[32 + l5] = (_Float16)(accO1[r] * inv);
        }
    }
    if (hi == 0) Mp[hf * NROWS + rowg0 + l5] = m_r;
    if (l5 == 0) {
#pragma unroll
        for (int r = 0; r < 16; r++) {
            int cr = (r & 3) + 8 * (r >> 2) + 4 * hi;
            Lp[hf * NROWS + rowg0 + cr] = accL[r];
        }
    }
}

// ---------- merge: out = w0*O0 + w1*O1, w_i = 2^(m_i-M) * l_i / sum ----------
__global__ __launch_bounds__(256) void attn_merge(float* __restrict__ outp, const _Float16* __restrict__ Op1,
                                                  const float* __restrict__ Mp, const float* __restrict__ Lp) {
    int t = blockIdx.x * 256 + threadIdx.x;   // 262144 threads: 4 per row
    int r = t >> 2;
    int dc = (t & 3) * 16;
    int bh = r >> 11, srow = r & 2047;
    int b = bh >> 4, h = bh & 15;
    float m0 = Mp[r], m1 = Mp[NROWS + r];
    float l0 = Lp[r], l1 = Lp[NROWS + r];
    float M = fmaxf(m0, m1);
    float w0 = __builtin_amdgcn_exp2f(m0 - M) * l0;
    float w1 = __builtin_amdgcn_exp2f(m1 - M) * l1;
    float inv = 1.0f / (w0 + w1);
    float a0 = w0 * inv, a1 = w1 * inv;
    float* op = outp + ((size_t)b * S_LEN + srow) * DMODEL + h * 64 + dc;
    const _Float16* o1 = Op1 + (size_t)r * 64 + dc;
#pragma unroll
    for (int q = 0; q < 4; q++) {
        float4 v0 = *(const float4*)(op + q * 4);
        h16x4 v1 = *(const h16x4*)(o1 + q * 4);
        v0.x = a0 * v0.x + a1 * (float)v1[0];
        v0.y = a0 * v0.y + a1 * (float)v1[1];
        v0.z = a0 * v0.z + a1 * (float)v1[2];
        v0.w = a0 * v0.w + a1 * (float)v1[3];
        *(float4*)(op + q * 4) = v0;
    }
}

extern "C" void kernel_launch(void* const* d_in, const int* in_sizes, int n_in,
                              void* d_out, int out_size, void* d_ws, size_t ws_size,
                              hipStream_t stream) {
    const float* X = (const float*)d_in[0];
    const float* W = (const float*)d_in[1];
    float* out = (float*)d_out;

    u16* Xb  = (u16*)d_ws;                        // 4096*1024 bf16 — dead after gemm
    u16* Wt  = Xb + (size_t)4096 * 1024;          // 3072*1024 bf16 — dead after gemm
    u16* QKV = Wt + (size_t)3072 * 1024;          // 4096*3072 bf16
    u16* Vtp = QKV + (size_t)4096 * 3072;         // 32*64*2048 bf16 (~48MB total)
    _Float16* Op1 = (_Float16*)Xb;                // 65536*64 fp16 = 8.4MB (== Xb size)
    float* Mp = (float*)Wt;                       // 2*65536 f32
    float* Lp = Mp + 2 * NROWS;                   // 2*65536 f32 (fits in Wt)

    cvt_x<<<4096, 256, 0, stream>>>(X, Xb);
    transpose_w<<<dim3(96, 32), 256, 0, stream>>>(W, Wt);
    qkv_gemm<<<dim3(24, 32), 256, 0, stream>>>(Xb, Wt, QKV);
    transpose_v<<<1024, 256, 0, stream>>>(QKV, Vtp);
    attn10<<<1024, 256, 0, stream>>>(QKV, Vtp, out, Op1, Mp, Lp);
    attn_merge<<<1024, 256, 0, stream>>>(out, Op1, Mp, Lp);
}

// Round 12
// 107.227 us; speedup vs baseline: 1.1524x; 1.1524x over previous
//
#include <hip/hip_runtime.h>
#include <hip/hip_bf16.h>
#include <math.h>

typedef __bf16 bf16x8 __attribute__((ext_vector_type(8)));
typedef float f32x4 __attribute__((ext_vector_type(4)));
typedef unsigned short u16x8 __attribute__((ext_vector_type(8)));
typedef unsigned short u16;

#define S_LEN 2048
#define DMODEL 1024
#define NH 16

__device__ __forceinline__ u16 f2bf(float f) {
    __bf16 b = (__bf16)f;
    return __builtin_bit_cast(u16, b);
}
__device__ __forceinline__ float bf2f(u16 u) {
    union { unsigned int i; float f; } v; v.i = ((unsigned int)u) << 16; return v.f;
}

// global -> LDS direct copy, 16B per lane (wave-uniform LDS base + lane*16).
__device__ __forceinline__ void gload16(const u16* g, u16* lds_base) {
    __builtin_amdgcn_global_load_lds(
        (const __attribute__((address_space(1))) unsigned int*)g,
        (__attribute__((address_space(3))) unsigned int*)lds_base,
        16, 0, 0);
}

// ---------- X f32 -> bf16 ----------
__global__ __launch_bounds__(256) void cvt_x(const float* __restrict__ in, u16* __restrict__ outp) {
    int i = (blockIdx.x * 256 + threadIdx.x) * 4;
    float4 v = *(const float4*)(in + i);
    outp[i + 0] = f2bf(v.x); outp[i + 1] = f2bf(v.y);
    outp[i + 2] = f2bf(v.z); outp[i + 3] = f2bf(v.w);
}

// ---------- W [1024][3072] f32 -> Wt [3072][1024] bf16 ----------
__global__ __launch_bounds__(256) void transpose_w(const float* __restrict__ W, u16* __restrict__ Wt) {
    __shared__ u16 tile[32][33];
    int n0 = blockIdx.x * 32, k0 = blockIdx.y * 32;
    int tx = threadIdx.x & 31, ty = threadIdx.x >> 5;
#pragma unroll
    for (int i = 0; i < 4; i++) {
        int k = ty + i * 8;
        tile[k][tx] = f2bf(W[(size_t)(k0 + k) * 3072 + n0 + tx]);
    }
    __syncthreads();
#pragma unroll
    for (int i = 0; i < 4; i++) {
        int n = ty + i * 8;
        Wt[(size_t)(n0 + n) * 1024 + k0 + tx] = tile[tx][n];
    }
}

// ---------- QKV GEMM (unchanged) ----------
__global__ __launch_bounds__(256) void qkv_gemm(const u16* __restrict__ A, const u16* __restrict__ Bt,
                                                u16* __restrict__ C) {
    __shared__ alignas(16) u16 As[128 * 64];
    __shared__ alignas(16) u16 Bs[128 * 64];
    const int tid = threadIdx.x, l = tid & 63, w = tid >> 6;
    const int bm = blockIdx.y, bn = blockIdx.x;
    const int wm = w >> 1, wn = w & 1;
    const int c0 = l & 15, g = l >> 4;
    f32x4 acc[4][4] = {};
    for (int kt = 0; kt < 1024; kt += 64) {
        __syncthreads();
#pragma unroll
        for (int n = 0; n < 4; n++) {
            int i = tid + n * 256;
            int r = i >> 3, c = i & 7;
            int cs = c ^ (r & 7);
            u16* dstA = As + (size_t)(w * 64 + n * 256) * 8;
            u16* dstB = Bs + (size_t)(w * 64 + n * 256) * 8;
            gload16(A + (size_t)(bm * 128 + r) * 1024 + kt + cs * 8, dstA);
            gload16(Bt + (size_t)(bn * 128 + r) * 1024 + kt + cs * 8, dstB);
        }
        __syncthreads();
#pragma unroll
        for (int kk = 0; kk < 2; kk++) {
            bf16x8 af[4], bfr[4];
#pragma unroll
            for (int m = 0; m < 4; m++) {
                int row = wm * 64 + m * 16 + c0;
                af[m] = *(const bf16x8*)((const char*)As + row * 128 + (((g + kk * 4) ^ (row & 7)) << 4));
            }
#pragma unroll
            for (int n = 0; n < 4; n++) {
                int row = wn * 64 + n * 16 + c0;
                bfr[n] = *(const bf16x8*)((const char*)Bs + row * 128 + (((g + kk * 4) ^ (row & 7)) << 4));
            }
#pragma unroll
            for (int m = 0; m < 4; m++)
#pragma unroll
                for (int n = 0; n < 4; n++)
                    acc[m][n] = __builtin_amdgcn_mfma_f32_16x16x32_bf16(af[m], bfr[n], acc[m][n], 0, 0, 0);
        }
    }
#pragma unroll
    for (int m = 0; m < 4; m++)
#pragma unroll
        for (int n = 0; n < 4; n++)
#pragma unroll
            for (int j = 0; j < 4; j++) {
                int row = bm * 128 + wm * 64 + m * 16 + 4 * g + j;
                int col = bn * 128 + wn * 64 + n * 16 + c0;
                C[(size_t)row * 3072 + col] = f2bf(acc[m][n][j]);
            }
}

// ---------- V -> permuted V^T: Vtp[bh][d][spos], spos = (s&~63) | perm(s&63) ----------
// perm(t): kb=t>>4, g=(t>>2)&3, j=t&3 -> pos = 32*(kb>>1) + 8*g + 4*(kb&1) + j  (R2-R9 verified)
__global__ __launch_bounds__(256) void transpose_v(const u16* __restrict__ QKV, u16* __restrict__ Vtp) {
    __shared__ u16 tile[64][72];
    const int bh = blockIdx.x >> 5, st = blockIdx.x & 31;
    const int b = bh >> 4, h = bh & 15;
    const u16* src = QKV + (size_t)b * S_LEN * 3072 + 2048 + h * 64;
    const int sl = threadIdx.x >> 2;
    const int cg = (threadIdx.x & 3) * 16;
#pragma unroll
    for (int ii = 0; ii < 2; ii++) {
        u16x8 v = *(const u16x8*)(src + (size_t)(st * 64 + sl) * 3072 + cg + ii * 8);
        *(u16x8*)&tile[sl][cg + ii * 8] = v;
    }
    __syncthreads();
    const int dl = threadIdx.x >> 2;
#pragma unroll
    for (int ii = 0; ii < 2; ii++) {
        u16x8 o;
#pragma unroll
        for (int q = 0; q < 8; q++) {
            int p = cg + ii * 8 + q;
            int kb = 2 * (p >> 5) + ((p >> 2) & 1);
            int t = kb * 16 + ((p >> 3) & 3) * 4 + (p & 3);
            o[q] = tile[t][dl];
        }
        *(u16x8*)(Vtp + ((size_t)bh * 64 + dl) * S_LEN + st * 64 + cg + ii * 8) = o;
    }
}

// ---------- Flash attention v11: attn9 datapath, KV-split x2 IN-BLOCK (8 waves / 512 thr:
// waves 0-3 = KV half 0, waves 4-7 = half 1, same 64 q-rows), in-LDS merge epilogue. ----------
__global__ __launch_bounds__(512, 4) void attn11(const u16* __restrict__ QKV, const u16* __restrict__ Vtp,
                                                 float* __restrict__ outp) {
    __shared__ alignas(16) u16 Ks[2][2][64 * 64];   // [hf][buf][key][d-chunk], chunk^=(key&7)
    __shared__ alignas(16) u16 Vs[2][2][64 * 64];   // [hf][buf][d][pos-chunk], chunk^=(d&7)
    const int bid = blockIdx.x;
    const int wg = ((bid & 7) << 7) | (bid >> 3);    // 1024 = 8*128, bijective XCD swizzle
    const int tid = threadIdx.x, l = tid & 63, w = tid >> 6;
    const int hf = w >> 2, wsub = w & 3;             // half & wave-within-half
    const int qt = wg & 31, bh = wg >> 5;
    const int b = bh >> 4, h = bh & 15;
    const int c0 = l & 15, g = l >> 4;
    const u16* Qb = QKV + (size_t)b * S_LEN * 3072 + h * 64;
    const u16* Kb = Qb + 1024;
    const u16* Vb = Vtp + (size_t)bh * 64 * S_LEN;
    const int kv0 = hf * 1024;
    const int qrow = qt * 64 + wsub * 16 + c0;

    // staging (per half, 256 threads): chunks {tid_h, tid_h+256}, pre-swizzled source col
    const int tid_h = tid & 255;
    const int r0 = tid_h >> 3, cs0 = (tid_h & 7) ^ (r0 & 7);
    const int i1 = tid_h + 256, r1 = i1 >> 3, cs1 = (i1 & 7) ^ (r1 & 7);
    const int dbA = (wsub * 64) * 8, dbB = (256 + wsub * 64) * 8;

    // unified LDS read offsets: off[x*2+kk] serves K (x=kb) and V (x=n) since key&7==d&7==c0&7
    int off[8];
#pragma unroll
    for (int x = 0; x < 4; x++)
#pragma unroll
        for (int kk = 0; kk < 2; kk++)
            off[x * 2 + kk] = (x * 16 + c0) * 128 + (((g + 4 * kk) ^ (c0 & 7)) << 4);

    // Q B-frags; fold (1/8)*log2(e)
    bf16x8 qf[2];
    {
        const float qs = 0.125f * 1.44269504f;
#pragma unroll
        for (int kk = 0; kk < 2; kk++) {
            u16x8 v = *(const u16x8*)(Qb + (size_t)qrow * 3072 + kk * 32 + g * 8);
            bf16x8 q;
#pragma unroll
            for (int j = 0; j < 8; j++) q[j] = (__bf16)(bf2f(v[j]) * qs);
            qf[kk] = q;
        }
    }
    bf16x8 vone;
#pragma unroll
    for (int j = 0; j < 8; j++) vone[j] = (__bf16)1.0f;

    float m_r = 0.f;             // baked scheme: sc accumulates S - m_r (per-lane q = c0)
    f32x4 accO[4] = {};
    f32x4 accL = {};

    // prologue: stage tile kv0 into buf 0 (each half stages its own)
    gload16(Kb + (size_t)(kv0 + r0) * 3072 + cs0 * 8, Ks[hf][0] + dbA);
    gload16(Kb + (size_t)(kv0 + r1) * 3072 + cs1 * 8, Ks[hf][0] + dbB);
    gload16(Vb + (size_t)r0 * S_LEN + kv0 + cs0 * 8, Vs[hf][0] + dbA);
    gload16(Vb + (size_t)r1 * S_LEN + kv0 + cs1 * 8, Vs[hf][0] + dbB);

    for (int t = 0; t < 16; t++) {
        const int cur = t & 1;
        __syncthreads();  // buf[cur] staged (vmcnt drained at barrier) + prev reads done
        if (t + 1 < 16) {
            const int kvn = kv0 + (t + 1) * 64;
            gload16(Kb + (size_t)(kvn + r0) * 3072 + cs0 * 8, Ks[hf][cur ^ 1] + dbA);
            gload16(Kb + (size_t)(kvn + r1) * 3072 + cs1 * 8, Ks[hf][cur ^ 1] + dbB);
            gload16(Vb + (size_t)r0 * S_LEN + kvn + cs0 * 8, Vs[hf][cur ^ 1] + dbA);
            gload16(Vb + (size_t)r1 * S_LEN + kvn + cs1 * 8, Vs[hf][cur ^ 1] + dbB);
        }
        const char* Kc = (const char*)Ks[hf][cur];
        const char* Vc = (const char*)Vs[hf][cur];
        // QK^T (swapped) with C-in = -m_r: sc = S - m_r directly
        f32x4 sc[4];
        const float nm = -m_r;
#pragma unroll
        for (int kb = 0; kb < 4; kb++) { sc[kb][0] = nm; sc[kb][1] = nm; sc[kb][2] = nm; sc[kb][3] = nm; }
        __builtin_amdgcn_s_setprio(1);
#pragma unroll
        for (int kb = 0; kb < 4; kb++)
#pragma unroll
            for (int kk = 0; kk < 2; kk++) {
                bf16x8 kf = *(const bf16x8*)(Kc + off[kb * 2 + kk]);
                sc[kb] = __builtin_amdgcn_mfma_f32_16x16x32_bf16(kf, qf[kk], sc[kb], 0, 0, 0);
            }
        __builtin_amdgcn_s_setprio(0);
        // V fragment reads (latency hides under softmax)
        bf16x8 vf[2][4];
#pragma unroll
        for (int kk = 0; kk < 2; kk++)
#pragma unroll
            for (int n = 0; n < 4; n++)
                vf[kk][n] = *(const bf16x8*)(Vc + off[n * 2 + kk]);
        // lane-local max of baked scores
        float m0 = fmaxf(fmaxf(sc[0][0], sc[0][1]), sc[0][2]);
        float m1 = fmaxf(fmaxf(sc[0][3], sc[1][0]), sc[1][1]);
        float m2 = fmaxf(fmaxf(sc[1][2], sc[1][3]), sc[2][0]);
        float m3 = fmaxf(fmaxf(sc[2][1], sc[2][2]), sc[2][3]);
        float m4 = fmaxf(fmaxf(sc[3][0], sc[3][1]), sc[3][2]);
        float mx = fmaxf(fmaxf(fmaxf(m0, m1), m2), fmaxf(fmaxf(m3, m4), sc[3][3]));
        // defer-max: rescale only if some lane's local growth exceeds 8 (log2 domain)
        if (!__all(mx <= 8.f)) {
            float mxr = fmaxf(mx, __shfl_xor(mx, 16));
            mxr = fmaxf(mxr, __shfl_xor(mxr, 32));        // per-q full-row baked max
            float adj = fmaxf(mxr, 0.f);
            float alpha = __builtin_amdgcn_exp2f(-adj);
            m_r += adj;
#pragma unroll
            for (int j = 0; j < 4; j++) {
                float aj = __shfl(alpha, 20 * g + j);
                accL[j] *= aj;
#pragma unroll
                for (int n = 0; n < 4; n++) accO[n][j] *= aj;
            }
#pragma unroll
            for (int kb = 0; kb < 4; kb++)
#pragma unroll
                for (int j = 0; j < 4; j++) sc[kb][j] -= adj;
        }
        // P = exp2(baked scores)
#pragma unroll
        for (int kb = 0; kb < 4; kb++)
#pragma unroll
            for (int j = 0; j < 4; j++)
                sc[kb][j] = __builtin_amdgcn_exp2f(sc[kb][j]);
        // PV + l (accL = P @ ones, rows match accO)
        __builtin_amdgcn_s_setprio(1);
#pragma unroll
        for (int kk = 0; kk < 2; kk++) {
            bf16x8 pf;
#pragma unroll
            for (int j = 0; j < 4; j++) {
                pf[j]     = (__bf16)sc[2 * kk][j];
                pf[j + 4] = (__bf16)sc[2 * kk + 1][j];
            }
            accL = __builtin_amdgcn_mfma_f32_16x16x32_bf16(pf, vone, accL, 0, 0, 0);
#pragma unroll
            for (int n = 0; n < 4; n++)
                accO[n] = __builtin_amdgcn_mfma_f32_16x16x32_bf16(pf, vf[kk][n], accO[n], 0, 0, 0);
        }
        __builtin_amdgcn_s_setprio(0);
    }
    // ---- in-block merge: half-1 dumps unnormalized partials to (dead) K/V LDS ----
    __syncthreads();   // all waves done reading K/V LDS
    float* Opart = (float*)&Ks[0][0][0];     // 64 x 65 f32 = 16.6KB (< 32KB Ks region)
    float* m1s   = (float*)&Vs[0][0][0];     // 64 f32
    float* l1s   = m1s + 64;                 // 64 f32
    if (hf == 1) {
#pragma unroll
        for (int j = 0; j < 4; j++) {
            int rj = wsub * 16 + 4 * g + j;
#pragma unroll
            for (int n = 0; n < 4; n++) Opart[rj * 65 + n * 16 + c0] = accO[n][j];
        }
        if (g == 0) m1s[wsub * 16 + c0] = m_r;
        if (c0 == 0) {
#pragma unroll
            for (int j = 0; j < 4; j++) l1s[wsub * 16 + 4 * g + j] = accL[j];
        }
    }
    __syncthreads();
    if (hf == 0) {
#pragma unroll
        for (int j = 0; j < 4; j++) {
            int rj = wsub * 16 + 4 * g + j;
            float m1v = m1s[rj], l1v = l1s[rj];
            float m0v = __shfl(m_r, 20 * g + j);           // stat for q-row rj
            float M = fmaxf(m0v, m1v);
            float a0 = __builtin_amdgcn_exp2f(m0v - M);
            float a1 = __builtin_amdgcn_exp2f(m1v - M);
            float inv = 1.0f / (a0 * accL[j] + a1 * l1v);
            float* op = outp + ((size_t)b * S_LEN + qt * 64 + rj) * DMODEL + h * 64;
#pragma unroll
            for (int n = 0; n < 4; n++)
                op[n * 16 + c0] = (a0 * accO[n][j] + a1 * Opart[rj * 65 + n * 16 + c0]) * inv;
        }
    }
}

extern "C" void kernel_launch(void* const* d_in, const int* in_sizes, int n_in,
                              void* d_out, int out_size, void* d_ws, size_t ws_size,
                              hipStream_t stream) {
    const float* X = (const float*)d_in[0];
    const float* W = (const float*)d_in[1];
    float* out = (float*)d_out;

    u16* Xb  = (u16*)d_ws;                        // 4096*1024 bf16
    u16* Wt  = Xb + (size_t)4096 * 1024;          // 3072*1024 bf16
    u16* QKV = Wt + (size_t)3072 * 1024;          // 4096*3072 bf16
    u16* Vtp = QKV + (size_t)4096 * 3072;         // 32*64*2048 bf16 (~48MB total)

    cvt_x<<<4096, 256, 0, stream>>>(X, Xb);
    transpose_w<<<dim3(96, 32), 256, 0, stream>>>(W, Wt);
    qkv_gemm<<<dim3(24, 32), 256, 0, stream>>>(Xb, Wt, QKV);
    transpose_v<<<1024, 256, 0, stream>>>(QKV, Vtp);
    attn11<<<1024, 512, 0, stream>>>(QKV, Vtp, out);
}

// Round 13
// 100.990 us; speedup vs baseline: 1.2235x; 1.0618x over previous
//
#include <hip/hip_runtime.h>
#include <hip/hip_bf16.h>
#include <math.h>

typedef __bf16 bf16x8 __attribute__((ext_vector_type(8)));
typedef float f32x4 __attribute__((ext_vector_type(4)));
typedef unsigned short u16x8 __attribute__((ext_vector_type(8)));
typedef unsigned short u16x4 __attribute__((ext_vector_type(4)));
typedef unsigned short u16;

#define S_LEN 2048
#define DMODEL 1024
#define NH 16

__device__ __forceinline__ u16 f2bf(float f) {
    __bf16 b = (__bf16)f;
    return __builtin_bit_cast(u16, b);
}
__device__ __forceinline__ float bf2f(u16 u) {
    union { unsigned int i; float f; } v; v.i = ((unsigned int)u) << 16; return v.f;
}

// global -> LDS direct copy, 16B per lane (wave-uniform LDS base + lane*16).
__device__ __forceinline__ void gload16(const u16* g, u16* lds_base) {
    __builtin_amdgcn_global_load_lds(
        (const __attribute__((address_space(1))) unsigned int*)g,
        (__attribute__((address_space(3))) unsigned int*)lds_base,
        16, 0, 0);
}

// ---------- prep: blocks [0,4096) = X f32->bf16 ; blocks [4096,7168) = W transpose ----------
__global__ __launch_bounds__(256) void prep(const float* __restrict__ X, u16* __restrict__ Xb,
                                            const float* __restrict__ W, u16* __restrict__ Wt) {
    __shared__ u16 tile[32][33];
    const int bid = blockIdx.x;
    if (bid < 4096) {
        int i = (bid * 256 + threadIdx.x) * 4;
        float4 v = *(const float4*)(X + i);
        Xb[i + 0] = f2bf(v.x); Xb[i + 1] = f2bf(v.y);
        Xb[i + 2] = f2bf(v.z); Xb[i + 3] = f2bf(v.w);
    } else {
        int bid2 = bid - 4096;
        int n0 = (bid2 % 96) * 32, k0 = (bid2 / 96) * 32;
        int tx = threadIdx.x & 31, ty = threadIdx.x >> 5;
#pragma unroll
        for (int i = 0; i < 4; i++) {
            int k = ty + i * 8;
            tile[k][tx] = f2bf(W[(size_t)(k0 + k) * 3072 + n0 + tx]);
        }
        __syncthreads();
#pragma unroll
        for (int i = 0; i < 4; i++) {
            int n = ty + i * 8;
            Wt[(size_t)(n0 + n) * 1024 + k0 + tx] = tile[tx][n];
        }
    }
}

// ---------- QKV GEMM with fused V-transpose epilogue ----------
// bn < 16: C[row][col] as before (Q,K thirds). bn >= 16 (V third): write acc directly to
// permuted Vtp[bh][d][spos], spos = (srow&~63) | (32*(m>>1)+8*g+4*(m&1)+j)  [t=m*16+4g+j].
__global__ __launch_bounds__(256) void qkv_gemm(const u16* __restrict__ A, const u16* __restrict__ Bt,
                                                u16* __restrict__ C, u16* __restrict__ Vtp) {
    __shared__ alignas(16) u16 As[128 * 64];
    __shared__ alignas(16) u16 Bs[128 * 64];
    const int tid = threadIdx.x, l = tid & 63, w = tid >> 6;
    const int bm = blockIdx.y, bn = blockIdx.x;
    const int wm = w >> 1, wn = w & 1;
    const int c0 = l & 15, g = l >> 4;
    f32x4 acc[4][4] = {};
    for (int kt = 0; kt < 1024; kt += 64) {
        __syncthreads();
#pragma unroll
        for (int n = 0; n < 4; n++) {
            int i = tid + n * 256;
            int r = i >> 3, c = i & 7;
            int cs = c ^ (r & 7);
            u16* dstA = As + (size_t)(w * 64 + n * 256) * 8;
            u16* dstB = Bs + (size_t)(w * 64 + n * 256) * 8;
            gload16(A + (size_t)(bm * 128 + r) * 1024 + kt + cs * 8, dstA);
            gload16(Bt + (size_t)(bn * 128 + r) * 1024 + kt + cs * 8, dstB);
        }
        __syncthreads();
#pragma unroll
        for (int kk = 0; kk < 2; kk++) {
            bf16x8 af[4], bfr[4];
#pragma unroll
            for (int m = 0; m < 4; m++) {
                int row = wm * 64 + m * 16 + c0;
                af[m] = *(const bf16x8*)((const char*)As + row * 128 + (((g + kk * 4) ^ (row & 7)) << 4));
            }
#pragma unroll
            for (int n = 0; n < 4; n++) {
                int row = wn * 64 + n * 16 + c0;
                bfr[n] = *(const bf16x8*)((const char*)Bs + row * 128 + (((g + kk * 4) ^ (row & 7)) << 4));
            }
#pragma unroll
            for (int m = 0; m < 4; m++)
#pragma unroll
                for (int n = 0; n < 4; n++)
                    acc[m][n] = __builtin_amdgcn_mfma_f32_16x16x32_bf16(af[m], bfr[n], acc[m][n], 0, 0, 0);
        }
    }
    if (bn < 16) {
        // Q/K thirds: normal C write
#pragma unroll
        for (int m = 0; m < 4; m++)
#pragma unroll
            for (int n = 0; n < 4; n++)
#pragma unroll
                for (int j = 0; j < 4; j++) {
                    int row = bm * 128 + wm * 64 + m * 16 + 4 * g + j;
                    int col = bn * 128 + wn * 64 + n * 16 + c0;
                    C[(size_t)row * 3072 + col] = f2bf(acc[m][n][j]);
                }
    } else {
        // V third: direct permuted-transpose store (4 consecutive spos per (m,n) -> 8B store)
        const int h = (bn - 16) * 2 + wn;
#pragma unroll
        for (int m = 0; m < 4; m++) {
            int srow_g = bm * 128 + wm * 64 + m * 16 + 4 * g;   // +j
            int b = srow_g >> 11;
            int srow = srow_g & 2047;
            int sbase = (srow & ~63) + 32 * (m >> 1) + 8 * g + 4 * (m & 1);
#pragma unroll
            for (int n = 0; n < 4; n++) {
                int d = n * 16 + c0;
                u16x4 v;
#pragma unroll
                for (int j = 0; j < 4; j++) v[j] = f2bf(acc[m][n][j]);
                *(u16x4*)(Vtp + ((size_t)(b * 16 + h) * 64 + d) * S_LEN + sbase) = v;
            }
        }
    }
}

// ---------- Flash attention v11 (unchanged champion): attn9 datapath, KV-split x2 IN-BLOCK
// (8 waves / 512 thr: waves 0-3 = KV half 0, waves 4-7 = half 1), in-LDS merge epilogue. ----------
__global__ __launch_bounds__(512, 4) void attn11(const u16* __restrict__ QKV, const u16* __restrict__ Vtp,
                                                 float* __restrict__ outp) {
    __shared__ alignas(16) u16 Ks[2][2][64 * 64];   // [hf][buf][key][d-chunk], chunk^=(key&7)
    __shared__ alignas(16) u16 Vs[2][2][64 * 64];   // [hf][buf][d][pos-chunk], chunk^=(d&7)
    const int bid = blockIdx.x;
    const int wg = ((bid & 7) << 7) | (bid >> 3);    // 1024 = 8*128, bijective XCD swizzle
    const int tid = threadIdx.x, l = tid & 63, w = tid >> 6;
    const int hf = w >> 2, wsub = w & 3;             // half & wave-within-half
    const int qt = wg & 31, bh = wg >> 5;
    const int b = bh >> 4, h = bh & 15;
    const int c0 = l & 15, g = l >> 4;
    const u16* Qb = QKV + (size_t)b * S_LEN * 3072 + h * 64;
    const u16* Kb = Qb + 1024;
    const u16* Vb = Vtp + (size_t)bh * 64 * S_LEN;
    const int kv0 = hf * 1024;
    const int qrow = qt * 64 + wsub * 16 + c0;

    const int tid_h = tid & 255;
    const int r0 = tid_h >> 3, cs0 = (tid_h & 7) ^ (r0 & 7);
    const int i1 = tid_h + 256, r1 = i1 >> 3, cs1 = (i1 & 7) ^ (r1 & 7);
    const int dbA = (wsub * 64) * 8, dbB = (256 + wsub * 64) * 8;

    int off[8];
#pragma unroll
    for (int x = 0; x < 4; x++)
#pragma unroll
        for (int kk = 0; kk < 2; kk++)
            off[x * 2 + kk] = (x * 16 + c0) * 128 + (((g + 4 * kk) ^ (c0 & 7)) << 4);

    bf16x8 qf[2];
    {
        const float qs = 0.125f * 1.44269504f;
#pragma unroll
        for (int kk = 0; kk < 2; kk++) {
            u16x8 v = *(const u16x8*)(Qb + (size_t)qrow * 3072 + kk * 32 + g * 8);
            bf16x8 q;
#pragma unroll
            for (int j = 0; j < 8; j++) q[j] = (__bf16)(bf2f(v[j]) * qs);
            qf[kk] = q;
        }
    }
    bf16x8 vone;
#pragma unroll
    for (int j = 0; j < 8; j++) vone[j] = (__bf16)1.0f;

    float m_r = 0.f;
    f32x4 accO[4] = {};
    f32x4 accL = {};

    gload16(Kb + (size_t)(kv0 + r0) * 3072 + cs0 * 8, Ks[hf][0] + dbA);
    gload16(Kb + (size_t)(kv0 + r1) * 3072 + cs1 * 8, Ks[hf][0] + dbB);
    gload16(Vb + (size_t)r0 * S_LEN + kv0 + cs0 * 8, Vs[hf][0] + dbA);
    gload16(Vb + (size_t)r1 * S_LEN + kv0 + cs1 * 8, Vs[hf][0] + dbB);

    for (int t = 0; t < 16; t++) {
        const int cur = t & 1;
        __syncthreads();
        if (t + 1 < 16) {
            const int kvn = kv0 + (t + 1) * 64;
            gload16(Kb + (size_t)(kvn + r0) * 3072 + cs0 * 8, Ks[hf][cur ^ 1] + dbA);
            gload16(Kb + (size_t)(kvn + r1) * 3072 + cs1 * 8, Ks[hf][cur ^ 1] + dbB);
            gload16(Vb + (size_t)r0 * S_LEN + kvn + cs0 * 8, Vs[hf][cur ^ 1] + dbA);
            gload16(Vb + (size_t)r1 * S_LEN + kvn + cs1 * 8, Vs[hf][cur ^ 1] + dbB);
        }
        const char* Kc = (const char*)Ks[hf][cur];
        const char* Vc = (const char*)Vs[hf][cur];
        f32x4 sc[4];
        const float nm = -m_r;
#pragma unroll
        for (int kb = 0; kb < 4; kb++) { sc[kb][0] = nm; sc[kb][1] = nm; sc[kb][2] = nm; sc[kb][3] = nm; }
        __builtin_amdgcn_s_setprio(1);
#pragma unroll
        for (int kb = 0; kb < 4; kb++)
#pragma unroll
            for (int kk = 0; kk < 2; kk++) {
                bf16x8 kf = *(const bf16x8*)(Kc + off[kb * 2 + kk]);
                sc[kb] = __builtin_amdgcn_mfma_f32_16x16x32_bf16(kf, qf[kk], sc[kb], 0, 0, 0);
            }
        __builtin_amdgcn_s_setprio(0);
        bf16x8 vf[2][4];
#pragma unroll
        for (int kk = 0; kk < 2; kk++)
#pragma unroll
            for (int n = 0; n < 4; n++)
                vf[kk][n] = *(const bf16x8*)(Vc + off[n * 2 + kk]);
        float m0 = fmaxf(fmaxf(sc[0][0], sc[0][1]), sc[0][2]);
        float m1 = fmaxf(fmaxf(sc[0][3], sc[1][0]), sc[1][1]);
        float m2 = fmaxf(fmaxf(sc[1][2], sc[1][3]), sc[2][0]);
        float m3 = fmaxf(fmaxf(sc[2][1], sc[2][2]), sc[2][3]);
        float m4 = fmaxf(fmaxf(sc[3][0], sc[3][1]), sc[3][2]);
        float mx = fmaxf(fmaxf(fmaxf(m0, m1), m2), fmaxf(fmaxf(m3, m4), sc[3][3]));
        if (!__all(mx <= 8.f)) {
            float mxr = fmaxf(mx, __shfl_xor(mx, 16));
            mxr = fmaxf(mxr, __shfl_xor(mxr, 32));
            float adj = fmaxf(mxr, 0.f);
            float alpha = __builtin_amdgcn_exp2f(-adj);
            m_r += adj;
#pragma unroll
            for (int j = 0; j < 4; j++) {
                float aj = __shfl(alpha, 20 * g + j);
                accL[j] *= aj;
#pragma unroll
                for (int n = 0; n < 4; n++) accO[n][j] *= aj;
            }
#pragma unroll
            for (int kb = 0; kb < 4; kb++)
#pragma unroll
                for (int j = 0; j < 4; j++) sc[kb][j] -= adj;
        }
#pragma unroll
        for (int kb = 0; kb < 4; kb++)
#pragma unroll
            for (int j = 0; j < 4; j++)
                sc[kb][j] = __builtin_amdgcn_exp2f(sc[kb][j]);
        __builtin_amdgcn_s_setprio(1);
#pragma unroll
        for (int kk = 0; kk < 2; kk++) {
            bf16x8 pf;
#pragma unroll
            for (int j = 0; j < 4; j++) {
                pf[j]     = (__bf16)sc[2 * kk][j];
                pf[j + 4] = (__bf16)sc[2 * kk + 1][j];
            }
            accL = __builtin_amdgcn_mfma_f32_16x16x32_bf16(pf, vone, accL, 0, 0, 0);
#pragma unroll
            for (int n = 0; n < 4; n++)
                accO[n] = __builtin_amdgcn_mfma_f32_16x16x32_bf16(pf, vf[kk][n], accO[n], 0, 0, 0);
        }
        __builtin_amdgcn_s_setprio(0);
    }
    __syncthreads();
    float* Opart = (float*)&Ks[0][0][0];
    float* m1s   = (float*)&Vs[0][0][0];
    float* l1s   = m1s + 64;
    if (hf == 1) {
#pragma unroll
        for (int j = 0; j < 4; j++) {
            int rj = wsub * 16 + 4 * g + j;
#pragma unroll
            for (int n = 0; n < 4; n++) Opart[rj * 65 + n * 16 + c0] = accO[n][j];
        }
        if (g == 0) m1s[wsub * 16 + c0] = m_r;
        if (c0 == 0) {
#pragma unroll
            for (int j = 0; j < 4; j++) l1s[wsub * 16 + 4 * g + j] = accL[j];
        }
    }
    __syncthreads();
    if (hf == 0) {
#pragma unroll
        for (int j = 0; j < 4; j++) {
            int rj = wsub * 16 + 4 * g + j;
            float m1v = m1s[rj], l1v = l1s[rj];
            float m0v = __shfl(m_r, 20 * g + j);
            float M = fmaxf(m0v, m1v);
            float a0 = __builtin_amdgcn_exp2f(m0v - M);
            float a1 = __builtin_amdgcn_exp2f(m1v - M);
            float inv = 1.0f / (a0 * accL[j] + a1 * l1v);
            float* op = outp + ((size_t)b * S_LEN + qt * 64 + rj) * DMODEL + h * 64;
#pragma unroll
            for (int n = 0; n < 4; n++)
                op[n * 16 + c0] = (a0 * accO[n][j] + a1 * Opart[rj * 65 + n * 16 + c0]) * inv;
        }
    }
}

extern "C" void kernel_launch(void* const* d_in, const int* in_sizes, int n_in,
                              void* d_out, int out_size, void* d_ws, size_t ws_size,
                              hipStream_t stream) {
    const float* X = (const float*)d_in[0];
    const float* W = (const float*)d_in[1];
    float* out = (float*)d_out;

    u16* Xb  = (u16*)d_ws;                        // 4096*1024 bf16
    u16* Wt  = Xb + (size_t)4096 * 1024;          // 3072*1024 bf16
    u16* QKV = Wt + (size_t)3072 * 1024;          // 4096*3072 bf16 (V third unused now)
    u16* Vtp = QKV + (size_t)4096 * 3072;         // 32*64*2048 bf16 (~48MB total)

    prep<<<7168, 256, 0, stream>>>(X, Xb, W, Wt);
    qkv_gemm<<<dim3(24, 32), 256, 0, stream>>>(Xb, Wt, QKV, Vtp);
    attn11<<<1024, 512, 0, stream>>>(QKV, Vtp, out);
}